// Round 1
// baseline (7060.661 us; speedup 1.0000x reference)
//
#include <hip/hip_runtime.h>
#include <hip/hip_bf16.h>

// Problem dims
#define T_STEPS 2048
#define BATCH   256
#define INW     64
#define H1      1280
#define H4D     320
#define H8D     160
#define G4      640   // 4*H8
#define ONUM    32

typedef __attribute__((ext_vector_type(8))) short short8;   // 8 x bf16
typedef __attribute__((ext_vector_type(4))) float floatx4;
typedef __hip_bfloat16 bf16;

union frag8 { short8 v; uint2 u2[2]; };

__device__ __forceinline__ float b2f(bf16 v) { return __bfloat162float(v); }
__device__ __forceinline__ bf16  f2b(float v) { return __float2bfloat16(v); }
__device__ __forceinline__ float bfu(unsigned short u) { return __uint_as_float((unsigned)u << 16); }
__device__ __forceinline__ float fsig(float x)  { return __fdividef(1.0f, 1.0f + __expf(-x)); }
__device__ __forceinline__ float ftanh(float x) { return __fdividef(2.0f, 1.0f + __expf(-2.0f * x)) - 1.0f; }

// LDS-only barrier: drains ds ops, leaves global loads in flight (no vmcnt).
__device__ __forceinline__ void lds_barrier() {
  asm volatile("s_waitcnt lgkmcnt(0)\n\ts_barrier" ::: "memory");
}

// ---------------- cast fp32 -> bf16 (vectorized x4) ----------------
struct bf16x4 { bf16 a, b, c, d; };
__global__ void cast_f32_bf16_v4(const float* __restrict__ s, bf16* __restrict__ d, int n4) {
  int i = blockIdx.x * blockDim.x + threadIdx.x;
  if (i >= n4) return;
  float4 v = reinterpret_cast<const float4*>(s)[i];
  bf16x4 o{f2b(v.x), f2b(v.y), f2b(v.z), f2b(v.w)};
  reinterpret_cast<bf16x4*>(d)[i] = o;
}

// Permute W_ih rows to gate-interleaved order: Wp[ix*4+g][k] = Wih[g*160+ix][k].
// Makes the fused-GEMM gate output row-major coalesced while keeping recur's
// uint2 read pattern (gx[row][ix*4+g]) unchanged.
__global__ void cast_permute_wih(const float* __restrict__ s, bf16* __restrict__ d) {
  int i = blockIdx.x * blockDim.x + threadIdx.x;
  if (i >= G4 * (H4D / 4)) return;
  int p = i / (H4D / 4), k4 = (i - p * (H4D / 4)) * 4;
  int g = p & 3, ix = p >> 2;
  float4 v = *reinterpret_cast<const float4*>(&s[(size_t)(g * 160 + ix) * H4D + k4]);
  bf16x4 o{f2b(v.x), f2b(v.y), f2b(v.z), f2b(v.w)};
  *reinterpret_cast<bf16x4*>(&d[(size_t)p * H4D + k4]) = o;
}

// Shared scratch:
//  phase1: Y1s[64][72] (9216) + W2cs[320][72] (46080) = 55296
//  phase2: Y2s[64][328] (41984) + Wps[320][36] (23040) = 65024
//  recur : 21504
#define SMEM_BYTES 65024

// ---------------- fused fc1+fc2+ih GEMM: one block = 64 batch-time rows ----
// Y1 = leaky(X[64x64] @ W1^T) computed per 64-wide K-chunk (no recompute:
// fc2 N==320 means one block sees every fc1 column exactly once).
// Y2 = leaky(Y1-stream @ W2^T)  [64x320, accumulated in regs]
// G  = Y2 @ Wp^T + bih + bhh     [64x640, gate-interleaved, coalesced]
__device__ void fused_gemm(char* smem, int tid, int gb,
    const bf16* __restrict__ Xg, const bf16* __restrict__ W1g, const float* __restrict__ b1v,
    const bf16* __restrict__ W2g, const float* __restrict__ b2v,
    const bf16* __restrict__ Wpg, const float* __restrict__ bihv, const float* __restrict__ bhhv,
    bf16* __restrict__ gxw)
{
  bf16 (*Y1s)[72]  = reinterpret_cast<bf16 (*)[72]>(smem);           // fc1 chunk out
  bf16 (*W2cs)[72] = reinterpret_cast<bf16 (*)[72]>(smem + 9216);    // W2 K-chunk
  const int lane = tid & 63, wave = tid >> 6;
  const int mrow = lane & 15, quad = lane >> 4;
  const int wm = (wave >= 5) ? 1 : 0;       // M half (32 rows)
  const int wn = wave - wm * 5;             // N fifth (64 cols)
  const int fm = wave & 3;                  // fc1 m-tile (waves 0..7)
  const int fnp = (wave >> 2) & 1;          // fc1 n-pair
  const size_t R0 = (size_t)gb * 64;

  // X fragments are chunk-invariant: hold in regs for the whole phase 1.
  short8 xf0, xf1;
  if (wave < 8) {
    const bf16* xrow = Xg + (R0 + fm * 16 + mrow) * INW;
    xf0 = *reinterpret_cast<const short8*>(xrow + quad * 8);
    xf1 = *reinterpret_cast<const short8*>(xrow + 32 + quad * 8);
  }

  // Prologue: stage W2 chunk 0.
  short8 w2r[4];
#pragma unroll
  for (int i = 0; i < 4; ++i) {
    int v = tid + i * 640;
    w2r[i] = *reinterpret_cast<const short8*>(&W2g[(size_t)(v >> 3) * H1 + (v & 7) * 8]);
  }
#pragma unroll
  for (int i = 0; i < 4; ++i) {
    int v = tid + i * 640;
    *reinterpret_cast<short8*>(&W2cs[v >> 3][(v & 7) * 8]) = w2r[i];
  }

  floatx4 acc2[2][4] = {};

  // ---- phase 1: fc2 accumulation over 20 K-chunks of 64 (fc1 fused) ----
  for (int c = 0; c < 20; ++c) {
    // B: fc1 for this chunk (waves 0..7 compute the 64x64 Y1 tile)
    if (wave < 8) {
      const bf16* wr0 = W1g + (size_t)(c * 64 + (fnp * 2 + 0) * 16 + mrow) * INW;
      const bf16* wr1 = W1g + (size_t)(c * 64 + (fnp * 2 + 1) * 16 + mrow) * INW;
      short8 wf00 = *reinterpret_cast<const short8*>(wr0 + quad * 8);
      short8 wf01 = *reinterpret_cast<const short8*>(wr0 + 32 + quad * 8);
      short8 wf10 = *reinterpret_cast<const short8*>(wr1 + quad * 8);
      short8 wf11 = *reinterpret_cast<const short8*>(wr1 + 32 + quad * 8);
      floatx4 a10 = {}, a11 = {};
      a10 = __builtin_amdgcn_mfma_f32_16x16x32_bf16(xf0, wf00, a10, 0, 0, 0);
      a10 = __builtin_amdgcn_mfma_f32_16x16x32_bf16(xf1, wf01, a10, 0, 0, 0);
      a11 = __builtin_amdgcn_mfma_f32_16x16x32_bf16(xf0, wf10, a11, 0, 0, 0);
      a11 = __builtin_amdgcn_mfma_f32_16x16x32_bf16(xf1, wf11, a11, 0, 0, 0);
#pragma unroll
      for (int r = 0; r < 4; ++r) {
        int row = fm * 16 + quad * 4 + r;
        {
          int col = (fnp * 2 + 0) * 16 + mrow;
          float vv = a10[r] + b1v[c * 64 + col];
          Y1s[row][col] = f2b(vv > 0.0f ? vv : 0.01f * vv);
        }
        {
          int col = (fnp * 2 + 1) * 16 + mrow;
          float vv = a11[r] + b1v[c * 64 + col];
          Y1s[row][col] = f2b(vv > 0.0f ? vv : 0.01f * vv);
        }
      }
    }
    // A: prefetch next W2 chunk into regs (issued after B's loads so the
    //    compiler's counted vmcnt for B doesn't drain these).
    if (c < 19) {
#pragma unroll
      for (int i = 0; i < 4; ++i) {
        int v = tid + i * 640;
        w2r[i] = *reinterpret_cast<const short8*>(
            &W2g[(size_t)(v >> 3) * H1 + (c + 1) * 64 + (v & 7) * 8]);
      }
    }
    lds_barrier();   // C: Y1s visible
    // D: main fc2 MFMA (ratio 16 MFMA / 12 ds_read_b128)
#pragma unroll
    for (int kk = 0; kk < 2; ++kk) {
      short8 af0 = *reinterpret_cast<const short8*>(&Y1s[wm * 32 + mrow][kk * 32 + quad * 8]);
      short8 af1 = *reinterpret_cast<const short8*>(&Y1s[wm * 32 + 16 + mrow][kk * 32 + quad * 8]);
#pragma unroll
      for (int j = 0; j < 4; ++j) {
        short8 bfj = *reinterpret_cast<const short8*>(
            &W2cs[wn * 64 + j * 16 + mrow][kk * 32 + quad * 8]);
        acc2[0][j] = __builtin_amdgcn_mfma_f32_16x16x32_bf16(af0, bfj, acc2[0][j], 0, 0, 0);
        acc2[1][j] = __builtin_amdgcn_mfma_f32_16x16x32_bf16(af1, bfj, acc2[1][j], 0, 0, 0);
      }
    }
    lds_barrier();   // E: reads of chunk c done
    // F: store next W2 chunk (hidden latency: loaded one phase earlier)
    if (c < 19) {
#pragma unroll
      for (int i = 0; i < 4; ++i) {
        int v = tid + i * 640;
        *reinterpret_cast<short8*>(&W2cs[v >> 3][(v & 7) * 8]) = w2r[i];
      }
    }
  }

  // ---- transition: Y2 = leaky(acc2 + b2) into LDS; prefetch Wp chunk 0 ----
  bf16 (*Y2s)[328] = reinterpret_cast<bf16 (*)[328]>(smem);
  char* Wps = smem + 41984;   // [320][36] bf16, 8B-aligned rows (b64 access)
  short8 wpr[2];
#pragma unroll
  for (int i = 0; i < 2; ++i) {
    int v = tid + i * 640;
    wpr[i] = *reinterpret_cast<const short8*>(&Wpg[(size_t)(v >> 2) * H4D + (v & 3) * 8]);
  }
#pragma unroll
  for (int i = 0; i < 2; ++i) {
#pragma unroll
    for (int j = 0; j < 4; ++j) {
      int col = wn * 64 + j * 16 + mrow;
      float bb = b2v[col];
#pragma unroll
      for (int r = 0; r < 4; ++r) {
        int row = wm * 32 + i * 16 + quad * 4 + r;
        float vv = acc2[i][j][r] + bb;
        Y2s[row][col] = f2b(vv > 0.0f ? vv : 0.01f * vv);
      }
    }
  }
#pragma unroll
  for (int i = 0; i < 2; ++i) {
    int v = tid + i * 640;
    frag8 u; u.v = wpr[i];
    char* p = Wps + (size_t)(v >> 2) * 72 + (v & 3) * 16;
    *reinterpret_cast<uint2*>(p) = u.u2[0];
    *reinterpret_cast<uint2*>(p + 8) = u.u2[1];
  }
  lds_barrier();

  // ---- phase 2: gates = Y2 @ Wp^T, two N-halves of 320, K-chunks of 32 ----
  floatx4 ag[2][4];
  for (int t = 0; t < 20; ++t) {
    int h = t / 10, kc = t - h * 10;
    if (kc == 0) {
#pragma unroll
      for (int i = 0; i < 2; ++i)
#pragma unroll
        for (int j = 0; j < 4; ++j) ag[i][j] = (floatx4){0.f, 0.f, 0.f, 0.f};
    }
    // B: fragments + MFMA
    short8 af0 = *reinterpret_cast<const short8*>(&Y2s[wm * 32 + mrow][kc * 32 + quad * 8]);
    short8 af1 = *reinterpret_cast<const short8*>(&Y2s[wm * 32 + 16 + mrow][kc * 32 + quad * 8]);
    frag8 bfj[4];
#pragma unroll
    for (int j = 0; j < 4; ++j) {
      const char* p = Wps + (size_t)(wn * 64 + j * 16 + mrow) * 72 + quad * 16;
      bfj[j].u2[0] = *reinterpret_cast<const uint2*>(p);
      bfj[j].u2[1] = *reinterpret_cast<const uint2*>(p + 8);
    }
#pragma unroll
    for (int j = 0; j < 4; ++j) {
      ag[0][j] = __builtin_amdgcn_mfma_f32_16x16x32_bf16(af0, bfj[j].v, ag[0][j], 0, 0, 0);
      ag[1][j] = __builtin_amdgcn_mfma_f32_16x16x32_bf16(af1, bfj[j].v, ag[1][j], 0, 0, 0);
    }
    // A: prefetch next Wp chunk
    if (t < 19) {
      int nh = (t + 1) / 10, nk = (t + 1) - nh * 10;
#pragma unroll
      for (int i = 0; i < 2; ++i) {
        int v = tid + i * 640;
        wpr[i] = *reinterpret_cast<const short8*>(
            &Wpg[(size_t)(nh * 320 + (v >> 2)) * H4D + nk * 32 + (v & 3) * 8]);
      }
    }
    lds_barrier();   // C
    if (t < 19) {
#pragma unroll
      for (int i = 0; i < 2; ++i) {
        int v = tid + i * 640;
        frag8 u; u.v = wpr[i];
        char* p = Wps + (size_t)(v >> 2) * 72 + (v & 3) * 16;
        *reinterpret_cast<uint2*>(p) = u.u2[0];
        *reinterpret_cast<uint2*>(p + 8) = u.u2[1];
      }
    }
    lds_barrier();   // E
    if (kc == 9) {
      // epilogue: gate-interleaved, coalesced (64 consecutive cols per wave/row)
#pragma unroll
      for (int j = 0; j < 4; ++j) {
        int p = h * 320 + wn * 64 + j * 16 + mrow;
        int g = p & 3, ix = p >> 2;
        float bb = bihv[g * 160 + ix] + bhhv[g * 160 + ix];
#pragma unroll
        for (int i = 0; i < 2; ++i)
#pragma unroll
          for (int r = 0; r < 4; ++r) {
            int row = wm * 32 + i * 16 + quad * 4 + r;
            gxw[(R0 + row) * 640 + p] = f2b(ag[i][j][r] + bb);
          }
      }
    }
  }
}

// ---------------- recur path (one block = 4 batch rows) — unchanged ----------
__device__ void recur_path(char* smem, int tid, int bid,
    const bf16* __restrict__ gx, const bf16* __restrict__ Whh,
    const bf16* __restrict__ W3w, const float* __restrict__ b3,
    bf16* __restrict__ h_ws, float* __restrict__ c_ws,
    float* __restrict__ outp, int Tc, int init)
{
  bf16 (*hbuf)[16][168] = reinterpret_cast<bf16 (*)[16][168]>(smem);     // 2 bufs
  bf16 (*w3s)[168] = reinterpret_cast<bf16 (*)[168]>(smem + 10752);      // 32 rows
  const int lane = tid & 63;
  const int wave = tid >> 6;
  const int mrow = lane & 15;
  const int quad = lane >> 4;
  const int bbase = bid * 4;
  const int ixg = wave * 16 + mrow;

  short8 whf[4][5];
#pragma unroll
  for (int g = 0; g < 4; ++g)
#pragma unroll
    for (int ks = 0; ks < 5; ++ks)
      whf[g][ks] = *reinterpret_cast<const short8*>(
          &Whh[(size_t)(g * 160 + ixg) * 160 + ks * 32 + quad * 8]);

  for (int e = tid; e < 32 * 160; e += 640) {
    int r = e / 160, cix = e - r * 160;
    w3s[r][cix] = W3w[e];
  }
  const float b3v = (wave < 2) ? b3[wave * 16 + mrow] : 0.0f;

  for (int e = tid; e < 2 * 16 * 168; e += 640)
    reinterpret_cast<bf16*>(hbuf)[e] = f2b(0.0f);
  __syncthreads();
  {
    int r = tid / 160, cix = tid - r * 160;
    hbuf[0][r * 4][cix] = init ? f2b(0.0f) : h_ws[(size_t)(bbase + r) * 160 + cix];
  }
  float c0 = init ? 0.0f : c_ws[(size_t)(bbase + quad) * 160 + ixg];
  __syncthreads();

  const uint2* __restrict__ gxp = reinterpret_cast<const uint2*>(gx);
  const size_t goff = (size_t)(bbase + quad) * 160 + ixg;
  uint2 gcur = gxp[goff], gnext = gcur;

  for (int t = 0; t < Tc; ++t) {
    const int rb = t & 1, wb = rb ^ 1;
    if (t + 1 < Tc) gnext = gxp[(size_t)(t + 1) * (256 * 160) + goff];

    short8 af[5];
#pragma unroll
    for (int ks = 0; ks < 5; ++ks)
      af[ks] = *reinterpret_cast<const short8*>(&hbuf[rb][mrow][ks * 32 + quad * 8]);

    if (wave < 2 && t > 0) {
      short8 w3f[5];
#pragma unroll
      for (int ks = 0; ks < 5; ++ks)
        w3f[ks] = *reinterpret_cast<const short8*>(&w3s[wave * 16 + mrow][ks * 32 + quad * 8]);
      floatx4 ya = {};
#pragma unroll
      for (int ks = 0; ks < 5; ++ks)
        ya = __builtin_amdgcn_mfma_f32_16x16x32_bf16(af[ks], w3f[ks], ya, 0, 0, 0);
      outp[((size_t)(t - 1) * 256 + bbase + quad) * 32 + wave * 16 + mrow] = ya[0] + b3v;
    }

    floatx4 acc[4] = {};
#pragma unroll
    for (int ks = 0; ks < 5; ++ks)
#pragma unroll
      for (int g = 0; g < 4; ++g)
        acc[g] = __builtin_amdgcn_mfma_f32_16x16x32_bf16(af[ks], whf[g][ks], acc[g], 0, 0, 0);

    {
      union { uint2 u; unsigned short s[4]; } q;
      q.u = gcur;
      float xi = acc[0][0] + bfu(q.s[0]);
      float xf = acc[1][0] + bfu(q.s[1]);
      float xg = acc[2][0] + bfu(q.s[2]);
      float xo = acc[3][0] + bfu(q.s[3]);
      float iv = fsig(xi), fv = fsig(xf), gvv = ftanh(xg), ov = fsig(xo);
      c0 = fv * c0 + iv * gvv;
      hbuf[wb][quad * 4][ixg] = f2b(ov * ftanh(c0));
    }
    gcur = gnext;
    lds_barrier();
  }

  if (wave < 2) {
    const int rb = Tc & 1;
    short8 af[5], w3f[5];
#pragma unroll
    for (int ks = 0; ks < 5; ++ks) {
      af[ks]  = *reinterpret_cast<const short8*>(&hbuf[rb][mrow][ks * 32 + quad * 8]);
      w3f[ks] = *reinterpret_cast<const short8*>(&w3s[wave * 16 + mrow][ks * 32 + quad * 8]);
    }
    floatx4 ya = {};
#pragma unroll
    for (int ks = 0; ks < 5; ++ks)
      ya = __builtin_amdgcn_mfma_f32_16x16x32_bf16(af[ks], w3f[ks], ya, 0, 0, 0);
    outp[((size_t)(Tc - 1) * 256 + bbase + quad) * 32 + wave * 16 + mrow] = ya[0] + b3v;
  }

  {
    int r = tid / 160, cix = tid - r * 160;
    h_ws[(size_t)(bbase + r) * 160 + cix] = hbuf[Tc & 1][r * 4][cix];
  }
  c_ws[(size_t)(bbase + quad) * 160 + ixg] = c0;
}

// ---------------- fused pipeline step ----------------
// blocks 0..63: recur(chunk L-1). blocks 64..: fused fc1+fc2+ih GEMM(chunk L).
__global__ __launch_bounds__(640, 5) void fused_step(
    int has_recur, const bf16* gxr, const bf16* Whh, const bf16* W3w,
    const float* b3, bf16* h_ws, float* c_ws, float* outp, int Tc, int init,
    int has_gemm, const bf16* Xc, const bf16* W1w, const float* b1v,
    const bf16* W2w, const float* b2v, const bf16* Wpw,
    const float* bihv, const float* bhhv, bf16* gxw)
{
  __shared__ __align__(16) char smem[SMEM_BYTES];
  const int tid = threadIdx.x;
  if (blockIdx.x < 64) {
    if (has_recur)
      recur_path(smem, tid, blockIdx.x, gxr, Whh, W3w, b3, h_ws, c_ws, outp, Tc, init);
    return;
  }
  if (has_gemm)
    fused_gemm(smem, tid, blockIdx.x - 64, Xc, W1w, b1v, W2w, b2v, Wpw, bihv, bhhv, gxw);
}

// ---------------- launch ----------------
extern "C" void kernel_launch(void* const* d_in, const int* in_sizes, int n_in,
                              void* d_out, int out_size, void* d_ws, size_t ws_size,
                              hipStream_t stream)
{
  const float* inp = (const float*)d_in[0];
  const float* W1  = (const float*)d_in[1];
  const float* b1  = (const float*)d_in[2];
  const float* W2  = (const float*)d_in[3];
  const float* b2  = (const float*)d_in[4];
  const float* Wih = (const float*)d_in[5];
  const float* Whh = (const float*)d_in[6];
  const float* bih = (const float*)d_in[7];
  const float* bhh = (const float*)d_in[8];
  const float* W3  = (const float*)d_in[9];
  const float* b3  = (const float*)d_in[10];
  float* out = (float*)d_out;

  char* ws = (char*)d_ws;
  size_t off = 0;
  auto alloc = [&](size_t bytes) -> char* {
    char* p = ws + off;
    off += (bytes + 255) & ~(size_t)255;
    return p;
  };

  bf16* inpb = (bf16*)alloc((size_t)T_STEPS * BATCH * INW * 2);
  bf16* w1b  = (bf16*)alloc((size_t)H1 * INW * 2);
  bf16* w2b  = (bf16*)alloc((size_t)H4D * H1 * 2);
  bf16* wpb  = (bf16*)alloc((size_t)G4 * H4D * 2);   // permuted W_ih
  bf16* whhb = (bf16*)alloc((size_t)G4 * H8D * 2);
  bf16* w3b  = (bf16*)alloc((size_t)ONUM * H8D * 2);
  bf16* h_ws = (bf16*)alloc((size_t)BATCH * H8D * 2);
  float* c_ws = (float*)alloc((size_t)BATCH * H8D * 4);
  size_t fixed = off;

  // time chunk; double-buffered gate buffer must fit the workspace
  int Tc = 128;
  while (Tc > 16) {
    size_t Mc = (size_t)Tc * BATCH;
    size_t need = fixed + 2 * ((Mc * G4 * 2 + 255) & ~(size_t)255);
    if (need <= ws_size) break;
    Tc >>= 1;
  }
  const size_t Mc = (size_t)Tc * BATCH;
  bf16* gxb[2];
  for (int i = 0; i < 2; ++i) gxb[i] = (bf16*)alloc(Mc * G4 * 2);

  // casts (every call; harness re-poisons ws before each timed launch)
  {
    int n4 = T_STEPS * BATCH * INW / 4;
    cast_f32_bf16_v4<<<(n4 + 255) / 256, 256, 0, stream>>>(inp, inpb, n4);
    n4 = H1 * INW / 4;
    cast_f32_bf16_v4<<<(n4 + 255) / 256, 256, 0, stream>>>(W1, w1b, n4);
    n4 = H4D * H1 / 4;
    cast_f32_bf16_v4<<<(n4 + 255) / 256, 256, 0, stream>>>(W2, w2b, n4);
    int np = G4 * (H4D / 4);
    cast_permute_wih<<<(np + 255) / 256, 256, 0, stream>>>(Wih, wpb);
    n4 = G4 * H8D / 4;
    cast_f32_bf16_v4<<<(n4 + 255) / 256, 256, 0, stream>>>(Whh, whhb, n4);
    n4 = ONUM * H8D / 4;
    cast_f32_bf16_v4<<<(n4 + 255) / 256, 256, 0, stream>>>(W3, w3b, n4);
  }

  const int nch = T_STEPS / Tc;
  const int nGB = (int)(Mc / 64);

  // Pipeline: launch L runs fused-GEMM(chunk L) and recur(chunk L-1).
  for (int L = 0; L <= nch; ++L) {
    const int hg = (L < nch) ? 1 : 0;
    const int hr = (L >= 1) ? 1 : 0;
    const bf16* Xc = inpb + (size_t)(hg ? L : 0) * Mc * INW;
    bf16* gxw = gxb[L & 1];
    const bf16* gxr = gxb[(L + 1) & 1];
    float* outp = hr ? (out + (size_t)(L - 1) * Tc * BATCH * ONUM) : out;

    fused_step<<<64 + (hg ? nGB : 0), 640, 0, stream>>>(
        hr, gxr, whhb, w3b, b3, h_ws, c_ws, outp, Tc, (L == 1) ? 1 : 0,
        hg, Xc, w1b, b1, w2b, b2, wpb, bih, bhh, gxw);
  }
}

// Round 2
// 2779.346 us; speedup vs baseline: 2.5404x; 2.5404x over previous
//
#include <hip/hip_runtime.h>
#include <hip/hip_bf16.h>

// Problem dims
#define T_STEPS 2048
#define BATCH   256
#define INW     64
#define H1      1280
#define H4D     320
#define H8D     160
#define G4      640   // 4*H8
#define ONUM    32

typedef __attribute__((ext_vector_type(8))) short short8;   // 8 x bf16
typedef __attribute__((ext_vector_type(4))) float floatx4;
typedef __hip_bfloat16 bf16;

union frag8 { short8 v; uint2 u2[2]; };

__device__ __forceinline__ float b2f(bf16 v) { return __bfloat162float(v); }
__device__ __forceinline__ bf16  f2b(float v) { return __float2bfloat16(v); }
__device__ __forceinline__ float bfu(unsigned short u) { return __uint_as_float((unsigned)u << 16); }
__device__ __forceinline__ float fsig(float x)  { return __fdividef(1.0f, 1.0f + __expf(-x)); }
__device__ __forceinline__ float ftanh(float x) { return __fdividef(2.0f, 1.0f + __expf(-2.0f * x)) - 1.0f; }

// LDS-only barrier: drains ds ops, leaves global loads in flight (no vmcnt).
__device__ __forceinline__ void lds_barrier() {
  asm volatile("s_waitcnt lgkmcnt(0)\n\ts_barrier" ::: "memory");
}

// ---------------- cast fp32 -> bf16 (vectorized x4) ----------------
struct bf16x4 { bf16 a, b, c, d; };
__global__ void cast_f32_bf16_v4(const float* __restrict__ s, bf16* __restrict__ d, int n4) {
  int i = blockIdx.x * blockDim.x + threadIdx.x;
  if (i >= n4) return;
  float4 v = reinterpret_cast<const float4*>(s)[i];
  bf16x4 o{f2b(v.x), f2b(v.y), f2b(v.z), f2b(v.w)};
  reinterpret_cast<bf16x4*>(d)[i] = o;
}

// Permute W_ih rows to gate-interleaved order: Wp[ix*4+g][k] = Wih[g*160+ix][k].
// Makes the fused-GEMM gate output row-major coalesced while keeping recur's
// uint2 read pattern (gx[row][ix*4+g]) unchanged.
__global__ void cast_permute_wih(const float* __restrict__ s, bf16* __restrict__ d) {
  int i = blockIdx.x * blockDim.x + threadIdx.x;
  if (i >= G4 * (H4D / 4)) return;
  int p = i / (H4D / 4), k4 = (i - p * (H4D / 4)) * 4;
  int g = p & 3, ix = p >> 2;
  float4 v = *reinterpret_cast<const float4*>(&s[(size_t)(g * 160 + ix) * H4D + k4]);
  bf16x4 o{f2b(v.x), f2b(v.y), f2b(v.z), f2b(v.w)};
  *reinterpret_cast<bf16x4*>(&d[(size_t)p * H4D + k4]) = o;
}

// Shared scratch:
//  phase1: Y1s[64][72] (9216) + W2cs[320][72] (46080) = 55296
//  phase2: Y2s[64][328] (41984) + Wps[320][36] (23040) = 65024
//  recur : 21504
#define SMEM_BYTES 65024

// ---------------- fused fc1+fc2+ih GEMM: one block = 64 batch-time rows ----
// Y1 = leaky(X[64x64] @ W1^T) computed per 64-wide K-chunk (no recompute:
// fc2 N==320 means one block sees every fc1 column exactly once).
// Y2 = leaky(Y1-stream @ W2^T)  [64x320, accumulated in regs]
// G  = Y2 @ Wp^T + bih + bhh     [64x640, gate-interleaved, coalesced]
__device__ void fused_gemm(char* smem, int tid, int gb,
    const bf16* __restrict__ Xg, const bf16* __restrict__ W1g, const float* __restrict__ b1v,
    const bf16* __restrict__ W2g, const float* __restrict__ b2v,
    const bf16* __restrict__ Wpg, const float* __restrict__ bihv, const float* __restrict__ bhhv,
    bf16* __restrict__ gxw)
{
  bf16 (*Y1s)[72]  = reinterpret_cast<bf16 (*)[72]>(smem);           // fc1 chunk out
  bf16 (*W2cs)[72] = reinterpret_cast<bf16 (*)[72]>(smem + 9216);    // W2 K-chunk
  const int lane = tid & 63, wave = tid >> 6;
  const int mrow = lane & 15, quad = lane >> 4;
  const int wm = (wave >= 5) ? 1 : 0;       // M half (32 rows)
  const int wn = wave - wm * 5;             // N fifth (64 cols)
  const int fm = wave & 3;                  // fc1 m-tile (waves 0..7)
  const int fnp = (wave >> 2) & 1;          // fc1 n-pair
  const size_t R0 = (size_t)gb * 64;

  // X fragments are chunk-invariant: hold in regs for the whole phase 1.
  short8 xf0, xf1;
  if (wave < 8) {
    const bf16* xrow = Xg + (R0 + fm * 16 + mrow) * INW;
    xf0 = *reinterpret_cast<const short8*>(xrow + quad * 8);
    xf1 = *reinterpret_cast<const short8*>(xrow + 32 + quad * 8);
  }

  // Prologue: prefetch W1 fragments for chunk 0 (reg double-buffer so the
  // fc1 MFMAs never consume a just-issued load — latency hides under fc2).
  short8 w1f[4];
  if (wave < 8) {
    const bf16* wr0 = W1g + (size_t)((fnp * 2 + 0) * 16 + mrow) * INW;
    const bf16* wr1 = W1g + (size_t)((fnp * 2 + 1) * 16 + mrow) * INW;
    w1f[0] = *reinterpret_cast<const short8*>(wr0 + quad * 8);
    w1f[1] = *reinterpret_cast<const short8*>(wr0 + 32 + quad * 8);
    w1f[2] = *reinterpret_cast<const short8*>(wr1 + quad * 8);
    w1f[3] = *reinterpret_cast<const short8*>(wr1 + 32 + quad * 8);
  }

  // Prologue: stage W2 chunk 0.
  short8 w2r[4];
#pragma unroll
  for (int i = 0; i < 4; ++i) {
    int v = tid + i * 640;
    w2r[i] = *reinterpret_cast<const short8*>(&W2g[(size_t)(v >> 3) * H1 + (v & 7) * 8]);
  }
#pragma unroll
  for (int i = 0; i < 4; ++i) {
    int v = tid + i * 640;
    *reinterpret_cast<short8*>(&W2cs[v >> 3][(v & 7) * 8]) = w2r[i];
  }

  floatx4 acc2[2][4] = {};

  // ---- phase 1: fc2 accumulation over 20 K-chunks of 64 (fc1 fused) ----
  for (int c = 0; c < 20; ++c) {
    // B: fc1 for this chunk (waves 0..7 compute the 64x64 Y1 tile)
    if (wave < 8) {
      floatx4 a10 = {}, a11 = {};
      a10 = __builtin_amdgcn_mfma_f32_16x16x32_bf16(xf0, w1f[0], a10, 0, 0, 0);
      a10 = __builtin_amdgcn_mfma_f32_16x16x32_bf16(xf1, w1f[1], a10, 0, 0, 0);
      a11 = __builtin_amdgcn_mfma_f32_16x16x32_bf16(xf0, w1f[2], a11, 0, 0, 0);
      a11 = __builtin_amdgcn_mfma_f32_16x16x32_bf16(xf1, w1f[3], a11, 0, 0, 0);
      // issue next chunk's W1 loads now; they land during fc2 of this chunk
      if (c < 19) {
        const bf16* wr0 = W1g + (size_t)((c + 1) * 64 + (fnp * 2 + 0) * 16 + mrow) * INW;
        const bf16* wr1 = W1g + (size_t)((c + 1) * 64 + (fnp * 2 + 1) * 16 + mrow) * INW;
        w1f[0] = *reinterpret_cast<const short8*>(wr0 + quad * 8);
        w1f[1] = *reinterpret_cast<const short8*>(wr0 + 32 + quad * 8);
        w1f[2] = *reinterpret_cast<const short8*>(wr1 + quad * 8);
        w1f[3] = *reinterpret_cast<const short8*>(wr1 + 32 + quad * 8);
      }
#pragma unroll
      for (int r = 0; r < 4; ++r) {
        int row = fm * 16 + quad * 4 + r;
        {
          int col = (fnp * 2 + 0) * 16 + mrow;
          float vv = a10[r] + b1v[c * 64 + col];
          Y1s[row][col] = f2b(vv > 0.0f ? vv : 0.01f * vv);
        }
        {
          int col = (fnp * 2 + 1) * 16 + mrow;
          float vv = a11[r] + b1v[c * 64 + col];
          Y1s[row][col] = f2b(vv > 0.0f ? vv : 0.01f * vv);
        }
      }
    }
    // A: prefetch next W2 chunk into regs (issued after B's loads so the
    //    compiler's counted vmcnt for B doesn't drain these).
    if (c < 19) {
#pragma unroll
      for (int i = 0; i < 4; ++i) {
        int v = tid + i * 640;
        w2r[i] = *reinterpret_cast<const short8*>(
            &W2g[(size_t)(v >> 3) * H1 + (c + 1) * 64 + (v & 7) * 8]);
      }
    }
    lds_barrier();   // C: Y1s visible
    // D: main fc2 MFMA (ratio 16 MFMA / 12 ds_read_b128)
#pragma unroll
    for (int kk = 0; kk < 2; ++kk) {
      short8 af0 = *reinterpret_cast<const short8*>(&Y1s[wm * 32 + mrow][kk * 32 + quad * 8]);
      short8 af1 = *reinterpret_cast<const short8*>(&Y1s[wm * 32 + 16 + mrow][kk * 32 + quad * 8]);
#pragma unroll
      for (int j = 0; j < 4; ++j) {
        short8 bfj = *reinterpret_cast<const short8*>(
            &W2cs[wn * 64 + j * 16 + mrow][kk * 32 + quad * 8]);
        acc2[0][j] = __builtin_amdgcn_mfma_f32_16x16x32_bf16(af0, bfj, acc2[0][j], 0, 0, 0);
        acc2[1][j] = __builtin_amdgcn_mfma_f32_16x16x32_bf16(af1, bfj, acc2[1][j], 0, 0, 0);
      }
    }
    lds_barrier();   // E: reads of chunk c done
    // F: store next W2 chunk (hidden latency: loaded one phase earlier)
    if (c < 19) {
#pragma unroll
      for (int i = 0; i < 4; ++i) {
        int v = tid + i * 640;
        *reinterpret_cast<short8*>(&W2cs[v >> 3][(v & 7) * 8]) = w2r[i];
      }
    }
  }

  // ---- transition: Y2 = leaky(acc2 + b2) into LDS; prefetch Wp chunk 0 ----
  bf16 (*Y2s)[328] = reinterpret_cast<bf16 (*)[328]>(smem);
  char* Wps = smem + 41984;   // [320][36] bf16, 8B-aligned rows (b64 access)
  short8 wpr[2];
#pragma unroll
  for (int i = 0; i < 2; ++i) {
    int v = tid + i * 640;
    wpr[i] = *reinterpret_cast<const short8*>(&Wpg[(size_t)(v >> 2) * H4D + (v & 3) * 8]);
  }
#pragma unroll
  for (int i = 0; i < 2; ++i) {
#pragma unroll
    for (int j = 0; j < 4; ++j) {
      int col = wn * 64 + j * 16 + mrow;
      float bb = b2v[col];
#pragma unroll
      for (int r = 0; r < 4; ++r) {
        int row = wm * 32 + i * 16 + quad * 4 + r;
        float vv = acc2[i][j][r] + bb;
        Y2s[row][col] = f2b(vv > 0.0f ? vv : 0.01f * vv);
      }
    }
  }
#pragma unroll
  for (int i = 0; i < 2; ++i) {
    int v = tid + i * 640;
    frag8 u; u.v = wpr[i];
    char* p = Wps + (size_t)(v >> 2) * 72 + (v & 3) * 16;
    *reinterpret_cast<uint2*>(p) = u.u2[0];
    *reinterpret_cast<uint2*>(p + 8) = u.u2[1];
  }
  lds_barrier();

  // ---- phase 2: gates = Y2 @ Wp^T, two N-halves of 320, K-chunks of 32 ----
  floatx4 ag[2][4];
  for (int t = 0; t < 20; ++t) {
    int h = t / 10, kc = t - h * 10;
    if (kc == 0) {
#pragma unroll
      for (int i = 0; i < 2; ++i)
#pragma unroll
        for (int j = 0; j < 4; ++j) ag[i][j] = (floatx4){0.f, 0.f, 0.f, 0.f};
    }
    // B: fragments + MFMA
    short8 af0 = *reinterpret_cast<const short8*>(&Y2s[wm * 32 + mrow][kc * 32 + quad * 8]);
    short8 af1 = *reinterpret_cast<const short8*>(&Y2s[wm * 32 + 16 + mrow][kc * 32 + quad * 8]);
    frag8 bfj[4];
#pragma unroll
    for (int j = 0; j < 4; ++j) {
      const char* p = Wps + (size_t)(wn * 64 + j * 16 + mrow) * 72 + quad * 16;
      bfj[j].u2[0] = *reinterpret_cast<const uint2*>(p);
      bfj[j].u2[1] = *reinterpret_cast<const uint2*>(p + 8);
    }
#pragma unroll
    for (int j = 0; j < 4; ++j) {
      ag[0][j] = __builtin_amdgcn_mfma_f32_16x16x32_bf16(af0, bfj[j].v, ag[0][j], 0, 0, 0);
      ag[1][j] = __builtin_amdgcn_mfma_f32_16x16x32_bf16(af1, bfj[j].v, ag[1][j], 0, 0, 0);
    }
    // A: prefetch next Wp chunk
    if (t < 19) {
      int nh = (t + 1) / 10, nk = (t + 1) - nh * 10;
#pragma unroll
      for (int i = 0; i < 2; ++i) {
        int v = tid + i * 640;
        wpr[i] = *reinterpret_cast<const short8*>(
            &Wpg[(size_t)(nh * 320 + (v >> 2)) * H4D + nk * 32 + (v & 3) * 8]);
      }
    }
    lds_barrier();   // C
    if (t < 19) {
#pragma unroll
      for (int i = 0; i < 2; ++i) {
        int v = tid + i * 640;
        frag8 u; u.v = wpr[i];
        char* p = Wps + (size_t)(v >> 2) * 72 + (v & 3) * 16;
        *reinterpret_cast<uint2*>(p) = u.u2[0];
        *reinterpret_cast<uint2*>(p + 8) = u.u2[1];
      }
    }
    lds_barrier();   // E
    if (kc == 9) {
      // epilogue: gate-interleaved, coalesced (64 consecutive cols per wave/row)
#pragma unroll
      for (int j = 0; j < 4; ++j) {
        int p = h * 320 + wn * 64 + j * 16 + mrow;
        int g = p & 3, ix = p >> 2;
        float bb = bihv[g * 160 + ix] + bhhv[g * 160 + ix];
#pragma unroll
        for (int i = 0; i < 2; ++i)
#pragma unroll
          for (int r = 0; r < 4; ++r) {
            int row = wm * 32 + i * 16 + quad * 4 + r;
            gxw[(R0 + row) * 640 + p] = f2b(ag[i][j][r] + bb);
          }
      }
    }
  }
}

// ---------------- recur path (one block = 4 batch rows) — unchanged ----------
__device__ void recur_path(char* smem, int tid, int bid,
    const bf16* __restrict__ gx, const bf16* __restrict__ Whh,
    const bf16* __restrict__ W3w, const float* __restrict__ b3,
    bf16* __restrict__ h_ws, float* __restrict__ c_ws,
    float* __restrict__ outp, int Tc, int init)
{
  bf16 (*hbuf)[16][168] = reinterpret_cast<bf16 (*)[16][168]>(smem);     // 2 bufs
  bf16 (*w3s)[168] = reinterpret_cast<bf16 (*)[168]>(smem + 10752);      // 32 rows
  const int lane = tid & 63;
  const int wave = tid >> 6;
  const int mrow = lane & 15;
  const int quad = lane >> 4;
  const int bbase = bid * 4;
  const int ixg = wave * 16 + mrow;

  short8 whf[4][5];
#pragma unroll
  for (int g = 0; g < 4; ++g)
#pragma unroll
    for (int ks = 0; ks < 5; ++ks)
      whf[g][ks] = *reinterpret_cast<const short8*>(
          &Whh[(size_t)(g * 160 + ixg) * 160 + ks * 32 + quad * 8]);

  for (int e = tid; e < 32 * 160; e += 640) {
    int r = e / 160, cix = e - r * 160;
    w3s[r][cix] = W3w[e];
  }
  const float b3v = (wave < 2) ? b3[wave * 16 + mrow] : 0.0f;

  for (int e = tid; e < 2 * 16 * 168; e += 640)
    reinterpret_cast<bf16*>(hbuf)[e] = f2b(0.0f);
  __syncthreads();
  {
    int r = tid / 160, cix = tid - r * 160;
    hbuf[0][r * 4][cix] = init ? f2b(0.0f) : h_ws[(size_t)(bbase + r) * 160 + cix];
  }
  float c0 = init ? 0.0f : c_ws[(size_t)(bbase + quad) * 160 + ixg];
  __syncthreads();

  const uint2* __restrict__ gxp = reinterpret_cast<const uint2*>(gx);
  const size_t goff = (size_t)(bbase + quad) * 160 + ixg;
  uint2 gcur = gxp[goff], gnext = gcur;

  for (int t = 0; t < Tc; ++t) {
    const int rb = t & 1, wb = rb ^ 1;
    if (t + 1 < Tc) gnext = gxp[(size_t)(t + 1) * (256 * 160) + goff];

    short8 af[5];
#pragma unroll
    for (int ks = 0; ks < 5; ++ks)
      af[ks] = *reinterpret_cast<const short8*>(&hbuf[rb][mrow][ks * 32 + quad * 8]);

    if (wave < 2 && t > 0) {
      short8 w3f[5];
#pragma unroll
      for (int ks = 0; ks < 5; ++ks)
        w3f[ks] = *reinterpret_cast<const short8*>(&w3s[wave * 16 + mrow][ks * 32 + quad * 8]);
      floatx4 ya = {};
#pragma unroll
      for (int ks = 0; ks < 5; ++ks)
        ya = __builtin_amdgcn_mfma_f32_16x16x32_bf16(af[ks], w3f[ks], ya, 0, 0, 0);
      outp[((size_t)(t - 1) * 256 + bbase + quad) * 32 + wave * 16 + mrow] = ya[0] + b3v;
    }

    floatx4 acc[4] = {};
#pragma unroll
    for (int ks = 0; ks < 5; ++ks)
#pragma unroll
      for (int g = 0; g < 4; ++g)
        acc[g] = __builtin_amdgcn_mfma_f32_16x16x32_bf16(af[ks], whf[g][ks], acc[g], 0, 0, 0);

    {
      union { uint2 u; unsigned short s[4]; } q;
      q.u = gcur;
      float xi = acc[0][0] + bfu(q.s[0]);
      float xf = acc[1][0] + bfu(q.s[1]);
      float xg = acc[2][0] + bfu(q.s[2]);
      float xo = acc[3][0] + bfu(q.s[3]);
      float iv = fsig(xi), fv = fsig(xf), gvv = ftanh(xg), ov = fsig(xo);
      c0 = fv * c0 + iv * gvv;
      hbuf[wb][quad * 4][ixg] = f2b(ov * ftanh(c0));
    }
    gcur = gnext;
    lds_barrier();
  }

  if (wave < 2) {
    const int rb = Tc & 1;
    short8 af[5], w3f[5];
#pragma unroll
    for (int ks = 0; ks < 5; ++ks) {
      af[ks]  = *reinterpret_cast<const short8*>(&hbuf[rb][mrow][ks * 32 + quad * 8]);
      w3f[ks] = *reinterpret_cast<const short8*>(&w3s[wave * 16 + mrow][ks * 32 + quad * 8]);
    }
    floatx4 ya = {};
#pragma unroll
    for (int ks = 0; ks < 5; ++ks)
      ya = __builtin_amdgcn_mfma_f32_16x16x32_bf16(af[ks], w3f[ks], ya, 0, 0, 0);
    outp[((size_t)(Tc - 1) * 256 + bbase + quad) * 32 + wave * 16 + mrow] = ya[0] + b3v;
  }

  {
    int r = tid / 160, cix = tid - r * 160;
    h_ws[(size_t)(bbase + r) * 160 + cix] = hbuf[Tc & 1][r * 4][cix];
  }
  c_ws[(size_t)(bbase + quad) * 160 + ixg] = c0;
}

// ---------------- fused pipeline step ----------------
// blocks 0..63: recur(chunk L-1). blocks 64..: fused fc1+fc2+ih GEMM(chunk L).
// NOTE: no waves/EU floor — (640,5) in R0 capped unified VGPR+AGPR at ~96/wave
// and spilled recur's whf[4][5] into a 128-step sequential loop (VGPR_Count 48,
// 2.4x regression). Let the allocator take what it needs.
__global__ __launch_bounds__(640, 1) void fused_step(
    int has_recur, const bf16* gxr, const bf16* Whh, const bf16* W3w,
    const float* b3, bf16* h_ws, float* c_ws, float* outp, int Tc, int init,
    int has_gemm, const bf16* Xc, const bf16* W1w, const float* b1v,
    const bf16* W2w, const float* b2v, const bf16* Wpw,
    const float* bihv, const float* bhhv, bf16* gxw)
{
  __shared__ __align__(16) char smem[SMEM_BYTES];
  const int tid = threadIdx.x;
  if (blockIdx.x < 64) {
    if (has_recur)
      recur_path(smem, tid, blockIdx.x, gxr, Whh, W3w, b3, h_ws, c_ws, outp, Tc, init);
    return;
  }
  if (has_gemm)
    fused_gemm(smem, tid, blockIdx.x - 64, Xc, W1w, b1v, W2w, b2v, Wpw, bihv, bhhv, gxw);
}

// ---------------- launch ----------------
extern "C" void kernel_launch(void* const* d_in, const int* in_sizes, int n_in,
                              void* d_out, int out_size, void* d_ws, size_t ws_size,
                              hipStream_t stream)
{
  const float* inp = (const float*)d_in[0];
  const float* W1  = (const float*)d_in[1];
  const float* b1  = (const float*)d_in[2];
  const float* W2  = (const float*)d_in[3];
  const float* b2  = (const float*)d_in[4];
  const float* Wih = (const float*)d_in[5];
  const float* Whh = (const float*)d_in[6];
  const float* bih = (const float*)d_in[7];
  const float* bhh = (const float*)d_in[8];
  const float* W3  = (const float*)d_in[9];
  const float* b3  = (const float*)d_in[10];
  float* out = (float*)d_out;

  char* ws = (char*)d_ws;
  size_t off = 0;
  auto alloc = [&](size_t bytes) -> char* {
    char* p = ws + off;
    off += (bytes + 255) & ~(size_t)255;
    return p;
  };

  bf16* inpb = (bf16*)alloc((size_t)T_STEPS * BATCH * INW * 2);
  bf16* w1b  = (bf16*)alloc((size_t)H1 * INW * 2);
  bf16* w2b  = (bf16*)alloc((size_t)H4D * H1 * 2);
  bf16* wpb  = (bf16*)alloc((size_t)G4 * H4D * 2);   // permuted W_ih
  bf16* whhb = (bf16*)alloc((size_t)G4 * H8D * 2);
  bf16* w3b  = (bf16*)alloc((size_t)ONUM * H8D * 2);
  bf16* h_ws = (bf16*)alloc((size_t)BATCH * H8D * 2);
  float* c_ws = (float*)alloc((size_t)BATCH * H8D * 4);
  size_t fixed = off;

  // time chunk; double-buffered gate buffer must fit the workspace
  int Tc = 128;
  while (Tc > 16) {
    size_t Mc = (size_t)Tc * BATCH;
    size_t need = fixed + 2 * ((Mc * G4 * 2 + 255) & ~(size_t)255);
    if (need <= ws_size) break;
    Tc >>= 1;
  }
  const size_t Mc = (size_t)Tc * BATCH;
  bf16* gxb[2];
  for (int i = 0; i < 2; ++i) gxb[i] = (bf16*)alloc(Mc * G4 * 2);

  // casts (every call; harness re-poisons ws before each timed launch)
  {
    int n4 = T_STEPS * BATCH * INW / 4;
    cast_f32_bf16_v4<<<(n4 + 255) / 256, 256, 0, stream>>>(inp, inpb, n4);
    n4 = H1 * INW / 4;
    cast_f32_bf16_v4<<<(n4 + 255) / 256, 256, 0, stream>>>(W1, w1b, n4);
    n4 = H4D * H1 / 4;
    cast_f32_bf16_v4<<<(n4 + 255) / 256, 256, 0, stream>>>(W2, w2b, n4);
    int np = G4 * (H4D / 4);
    cast_permute_wih<<<(np + 255) / 256, 256, 0, stream>>>(Wih, wpb);
    n4 = G4 * H8D / 4;
    cast_f32_bf16_v4<<<(n4 + 255) / 256, 256, 0, stream>>>(Whh, whhb, n4);
    n4 = ONUM * H8D / 4;
    cast_f32_bf16_v4<<<(n4 + 255) / 256, 256, 0, stream>>>(W3, w3b, n4);
  }

  const int nch = T_STEPS / Tc;
  const int nGB = (int)(Mc / 64);

  // Pipeline: launch L runs fused-GEMM(chunk L) and recur(chunk L-1).
  for (int L = 0; L <= nch; ++L) {
    const int hg = (L < nch) ? 1 : 0;
    const int hr = (L >= 1) ? 1 : 0;
    const bf16* Xc = inpb + (size_t)(hg ? L : 0) * Mc * INW;
    bf16* gxw = gxb[L & 1];
    const bf16* gxr = gxb[(L + 1) & 1];
    float* outp = hr ? (out + (size_t)(L - 1) * Tc * BATCH * ONUM) : out;

    fused_step<<<64 + (hg ? nGB : 0), 640, 0, stream>>>(
        hr, gxr, whhb, w3b, b3, h_ws, c_ws, outp, Tc, (L == 1) ? 1 : 0,
        hg, Xc, w1b, b1, w2b, b2, wpb, bih, bhh, gxw);
  }
}

// Round 3
// 2763.676 us; speedup vs baseline: 2.5548x; 1.0057x over previous
//
#include <hip/hip_runtime.h>
#include <hip/hip_bf16.h>

// Problem dims
#define T_STEPS 2048
#define BATCH   256
#define INW     64
#define H1      1280
#define H4D     320
#define H8D     160
#define G4      640   // 4*H8
#define ONUM    32

typedef __attribute__((ext_vector_type(8))) short short8;   // 8 x bf16
typedef __attribute__((ext_vector_type(4))) float floatx4;
typedef __hip_bfloat16 bf16;

union frag8 { short8 v; uint2 u2[2]; };

__device__ __forceinline__ float b2f(bf16 v) { return __bfloat162float(v); }
__device__ __forceinline__ bf16  f2b(float v) { return __float2bfloat16(v); }
__device__ __forceinline__ float bfu(unsigned short u) { return __uint_as_float((unsigned)u << 16); }
__device__ __forceinline__ float fsig(float x)  { return __fdividef(1.0f, 1.0f + __expf(-x)); }
__device__ __forceinline__ float ftanh(float x) { return __fdividef(2.0f, 1.0f + __expf(-2.0f * x)) - 1.0f; }

// LDS-only barrier: drains ds ops, leaves global loads in flight (no vmcnt).
__device__ __forceinline__ void lds_barrier() {
  asm volatile("s_waitcnt lgkmcnt(0)\n\ts_barrier" ::: "memory");
}

// ---------------- cast fp32 -> bf16 (vectorized x4) ----------------
struct bf16x4 { bf16 a, b, c, d; };
__global__ void cast_f32_bf16_v4(const float* __restrict__ s, bf16* __restrict__ d, int n4) {
  int i = blockIdx.x * blockDim.x + threadIdx.x;
  if (i >= n4) return;
  float4 v = reinterpret_cast<const float4*>(s)[i];
  bf16x4 o{f2b(v.x), f2b(v.y), f2b(v.z), f2b(v.w)};
  reinterpret_cast<bf16x4*>(d)[i] = o;
}

// Permute W_ih rows to gate-interleaved order: Wp[ix*4+g][k] = Wih[g*160+ix][k].
__global__ void cast_permute_wih(const float* __restrict__ s, bf16* __restrict__ d) {
  int i = blockIdx.x * blockDim.x + threadIdx.x;
  if (i >= G4 * (H4D / 4)) return;
  int p = i / (H4D / 4), k4 = (i - p * (H4D / 4)) * 4;
  int g = p & 3, ix = p >> 2;
  float4 v = *reinterpret_cast<const float4*>(&s[(size_t)(g * 160 + ix) * H4D + k4]);
  bf16x4 o{f2b(v.x), f2b(v.y), f2b(v.z), f2b(v.w)};
  *reinterpret_cast<bf16x4*>(&d[(size_t)p * H4D + k4]) = o;
}

// Shared scratch:
//  gemm phase1: Y1s[64][72] (9216) + W2cs[320][72] (46080) = 55296
//  gemm phase2: Y2s[64][328] (41984) + Wps[320][36] (23040) = 65024
//  recur      : hbuf only, 10752
#define SMEM_BYTES 65024

// ---------------- fused fc1+fc2+ih GEMM: one block = 64 batch-time rows ----
__device__ void fused_gemm(char* smem, int tid, int gb,
    const bf16* __restrict__ Xg, const bf16* __restrict__ W1g, const float* __restrict__ b1v,
    const bf16* __restrict__ W2g, const float* __restrict__ b2v,
    const bf16* __restrict__ Wpg, const float* __restrict__ bihv, const float* __restrict__ bhhv,
    bf16* __restrict__ gxw)
{
  bf16 (*Y1s)[72]  = reinterpret_cast<bf16 (*)[72]>(smem);           // fc1 chunk out
  bf16 (*W2cs)[72] = reinterpret_cast<bf16 (*)[72]>(smem + 9216);    // W2 K-chunk
  const int lane = tid & 63, wave = tid >> 6;
  const int mrow = lane & 15, quad = lane >> 4;
  const int wm = (wave >= 5) ? 1 : 0;       // M half (32 rows)
  const int wn = wave - wm * 5;             // N fifth (64 cols)
  const int fm = wave & 3;                  // fc1 m-tile (waves 0..7)
  const int fnp = (wave >> 2) & 1;          // fc1 n-pair
  const size_t R0 = (size_t)gb * 64;

  // X fragments are chunk-invariant: hold in regs for the whole phase 1.
  short8 xf0, xf1;
  if (wave < 8) {
    const bf16* xrow = Xg + (R0 + fm * 16 + mrow) * INW;
    xf0 = *reinterpret_cast<const short8*>(xrow + quad * 8);
    xf1 = *reinterpret_cast<const short8*>(xrow + 32 + quad * 8);
  }

  // Prologue: prefetch W1 fragments for chunk 0 (reg double-buffer so the
  // fc1 MFMAs never consume a just-issued load — latency hides under fc2).
  short8 w1f[4];
  if (wave < 8) {
    const bf16* wr0 = W1g + (size_t)((fnp * 2 + 0) * 16 + mrow) * INW;
    const bf16* wr1 = W1g + (size_t)((fnp * 2 + 1) * 16 + mrow) * INW;
    w1f[0] = *reinterpret_cast<const short8*>(wr0 + quad * 8);
    w1f[1] = *reinterpret_cast<const short8*>(wr0 + 32 + quad * 8);
    w1f[2] = *reinterpret_cast<const short8*>(wr1 + quad * 8);
    w1f[3] = *reinterpret_cast<const short8*>(wr1 + 32 + quad * 8);
  }

  // Prologue: stage W2 chunk 0.
  short8 w2r[4];
#pragma unroll
  for (int i = 0; i < 4; ++i) {
    int v = tid + i * 640;
    w2r[i] = *reinterpret_cast<const short8*>(&W2g[(size_t)(v >> 3) * H1 + (v & 7) * 8]);
  }
#pragma unroll
  for (int i = 0; i < 4; ++i) {
    int v = tid + i * 640;
    *reinterpret_cast<short8*>(&W2cs[v >> 3][(v & 7) * 8]) = w2r[i];
  }

  floatx4 acc2[2][4] = {};

  // ---- phase 1: fc2 accumulation over 20 K-chunks of 64 (fc1 fused) ----
  for (int c = 0; c < 20; ++c) {
    if (wave < 8) {
      floatx4 a10 = {}, a11 = {};
      a10 = __builtin_amdgcn_mfma_f32_16x16x32_bf16(xf0, w1f[0], a10, 0, 0, 0);
      a10 = __builtin_amdgcn_mfma_f32_16x16x32_bf16(xf1, w1f[1], a10, 0, 0, 0);
      a11 = __builtin_amdgcn_mfma_f32_16x16x32_bf16(xf0, w1f[2], a11, 0, 0, 0);
      a11 = __builtin_amdgcn_mfma_f32_16x16x32_bf16(xf1, w1f[3], a11, 0, 0, 0);
      if (c < 19) {
        const bf16* wr0 = W1g + (size_t)((c + 1) * 64 + (fnp * 2 + 0) * 16 + mrow) * INW;
        const bf16* wr1 = W1g + (size_t)((c + 1) * 64 + (fnp * 2 + 1) * 16 + mrow) * INW;
        w1f[0] = *reinterpret_cast<const short8*>(wr0 + quad * 8);
        w1f[1] = *reinterpret_cast<const short8*>(wr0 + 32 + quad * 8);
        w1f[2] = *reinterpret_cast<const short8*>(wr1 + quad * 8);
        w1f[3] = *reinterpret_cast<const short8*>(wr1 + 32 + quad * 8);
      }
#pragma unroll
      for (int r = 0; r < 4; ++r) {
        int row = fm * 16 + quad * 4 + r;
        {
          int col = (fnp * 2 + 0) * 16 + mrow;
          float vv = a10[r] + b1v[c * 64 + col];
          Y1s[row][col] = f2b(vv > 0.0f ? vv : 0.01f * vv);
        }
        {
          int col = (fnp * 2 + 1) * 16 + mrow;
          float vv = a11[r] + b1v[c * 64 + col];
          Y1s[row][col] = f2b(vv > 0.0f ? vv : 0.01f * vv);
        }
      }
    }
    if (c < 19) {
#pragma unroll
      for (int i = 0; i < 4; ++i) {
        int v = tid + i * 640;
        w2r[i] = *reinterpret_cast<const short8*>(
            &W2g[(size_t)(v >> 3) * H1 + (c + 1) * 64 + (v & 7) * 8]);
      }
    }
    lds_barrier();   // Y1s visible
#pragma unroll
    for (int kk = 0; kk < 2; ++kk) {
      short8 af0 = *reinterpret_cast<const short8*>(&Y1s[wm * 32 + mrow][kk * 32 + quad * 8]);
      short8 af1 = *reinterpret_cast<const short8*>(&Y1s[wm * 32 + 16 + mrow][kk * 32 + quad * 8]);
#pragma unroll
      for (int j = 0; j < 4; ++j) {
        short8 bfj = *reinterpret_cast<const short8*>(
            &W2cs[wn * 64 + j * 16 + mrow][kk * 32 + quad * 8]);
        acc2[0][j] = __builtin_amdgcn_mfma_f32_16x16x32_bf16(af0, bfj, acc2[0][j], 0, 0, 0);
        acc2[1][j] = __builtin_amdgcn_mfma_f32_16x16x32_bf16(af1, bfj, acc2[1][j], 0, 0, 0);
      }
    }
    lds_barrier();   // reads of chunk c done
    if (c < 19) {
#pragma unroll
      for (int i = 0; i < 4; ++i) {
        int v = tid + i * 640;
        *reinterpret_cast<short8*>(&W2cs[v >> 3][(v & 7) * 8]) = w2r[i];
      }
    }
  }

  // ---- transition: Y2 = leaky(acc2 + b2) into LDS; prefetch Wp chunk 0 ----
  bf16 (*Y2s)[328] = reinterpret_cast<bf16 (*)[328]>(smem);
  char* Wps = smem + 41984;   // [320][36] bf16, 8B-aligned rows (b64 access)
  short8 wpr[2];
#pragma unroll
  for (int i = 0; i < 2; ++i) {
    int v = tid + i * 640;
    wpr[i] = *reinterpret_cast<const short8*>(&Wpg[(size_t)(v >> 2) * H4D + (v & 3) * 8]);
  }
#pragma unroll
  for (int i = 0; i < 2; ++i) {
#pragma unroll
    for (int j = 0; j < 4; ++j) {
      int col = wn * 64 + j * 16 + mrow;
      float bb = b2v[col];
#pragma unroll
      for (int r = 0; r < 4; ++r) {
        int row = wm * 32 + i * 16 + quad * 4 + r;
        float vv = acc2[i][j][r] + bb;
        Y2s[row][col] = f2b(vv > 0.0f ? vv : 0.01f * vv);
      }
    }
  }
#pragma unroll
  for (int i = 0; i < 2; ++i) {
    int v = tid + i * 640;
    frag8 u; u.v = wpr[i];
    char* p = Wps + (size_t)(v >> 2) * 72 + (v & 3) * 16;
    *reinterpret_cast<uint2*>(p) = u.u2[0];
    *reinterpret_cast<uint2*>(p + 8) = u.u2[1];
  }
  lds_barrier();

  // ---- phase 2: gates = Y2 @ Wp^T, two N-halves of 320, K-chunks of 32 ----
  floatx4 ag[2][4];
  for (int t = 0; t < 20; ++t) {
    int h = t / 10, kc = t - h * 10;
    if (kc == 0) {
#pragma unroll
      for (int i = 0; i < 2; ++i)
#pragma unroll
        for (int j = 0; j < 4; ++j) ag[i][j] = (floatx4){0.f, 0.f, 0.f, 0.f};
    }
    short8 af0 = *reinterpret_cast<const short8*>(&Y2s[wm * 32 + mrow][kc * 32 + quad * 8]);
    short8 af1 = *reinterpret_cast<const short8*>(&Y2s[wm * 32 + 16 + mrow][kc * 32 + quad * 8]);
    frag8 bfj[4];
#pragma unroll
    for (int j = 0; j < 4; ++j) {
      const char* p = Wps + (size_t)(wn * 64 + j * 16 + mrow) * 72 + quad * 16;
      bfj[j].u2[0] = *reinterpret_cast<const uint2*>(p);
      bfj[j].u2[1] = *reinterpret_cast<const uint2*>(p + 8);
    }
#pragma unroll
    for (int j = 0; j < 4; ++j) {
      ag[0][j] = __builtin_amdgcn_mfma_f32_16x16x32_bf16(af0, bfj[j].v, ag[0][j], 0, 0, 0);
      ag[1][j] = __builtin_amdgcn_mfma_f32_16x16x32_bf16(af1, bfj[j].v, ag[1][j], 0, 0, 0);
    }
    if (t < 19) {
      int nh = (t + 1) / 10, nk = (t + 1) - nh * 10;
#pragma unroll
      for (int i = 0; i < 2; ++i) {
        int v = tid + i * 640;
        wpr[i] = *reinterpret_cast<const short8*>(
            &Wpg[(size_t)(nh * 320 + (v >> 2)) * H4D + nk * 32 + (v & 3) * 8]);
      }
    }
    lds_barrier();
    if (t < 19) {
#pragma unroll
      for (int i = 0; i < 2; ++i) {
        int v = tid + i * 640;
        frag8 u; u.v = wpr[i];
        char* p = Wps + (size_t)(v >> 2) * 72 + (v & 3) * 16;
        *reinterpret_cast<uint2*>(p) = u.u2[0];
        *reinterpret_cast<uint2*>(p + 8) = u.u2[1];
      }
    }
    lds_barrier();
    if (kc == 9) {
      // epilogue: gate-interleaved, coalesced (64 consecutive cols per wave/row)
#pragma unroll
      for (int j = 0; j < 4; ++j) {
        int p = h * 320 + wn * 64 + j * 16 + mrow;
        int g = p & 3, ix = p >> 2;
        float bb = bihv[g * 160 + ix] + bhhv[g * 160 + ix];
#pragma unroll
        for (int i = 0; i < 2; ++i)
#pragma unroll
          for (int r = 0; r < 4; ++r) {
            int row = wm * 32 + i * 16 + quad * 4 + r;
            gxw[(R0 + row) * 640 + p] = f2b(ag[i][j][r] + bb);
          }
      }
    }
  }
}

// ---------------- recur path (one block = 4 batch rows) ----------------
// Changes vs R2: (1) y=h@W3 removed from the step chain — h_t streamed to a
// global history buffer (fire-and-forget b16 store, never waited), y done by
// ygemm blocks two dispatches later. (2) t-loop unrolled x2 with two rotating
// gx prefetch registers: load for step t+2 issued at end of step t -> ~2
// step-times of HBM-latency cover, and no gcur=gnext copy forcing a per-step
// vmcnt drain.
__device__ void recur_path(char* smem, int tid, int bid,
    const bf16* __restrict__ gx, const bf16* __restrict__ Whh,
    bf16* __restrict__ h_ws, float* __restrict__ c_ws,
    bf16* __restrict__ hh, int Tc, int init)
{
  bf16 (*hbuf)[16][168] = reinterpret_cast<bf16 (*)[16][168]>(smem);     // 2 bufs
  const int lane = tid & 63;
  const int wave = tid >> 6;
  const int mrow = lane & 15;
  const int quad = lane >> 4;
  const int bbase = bid * 4;
  const int ixg = wave * 16 + mrow;

  short8 whf[4][5];
#pragma unroll
  for (int g = 0; g < 4; ++g)
#pragma unroll
    for (int ks = 0; ks < 5; ++ks)
      whf[g][ks] = *reinterpret_cast<const short8*>(
          &Whh[(size_t)(g * 160 + ixg) * 160 + ks * 32 + quad * 8]);

  for (int e = tid; e < 2 * 16 * 168; e += 640)
    reinterpret_cast<bf16*>(hbuf)[e] = f2b(0.0f);
  __syncthreads();
  {
    int r = tid / 160, cix = tid - r * 160;
    hbuf[0][r * 4][cix] = init ? f2b(0.0f) : h_ws[(size_t)(bbase + r) * 160 + cix];
  }
  float c0 = init ? 0.0f : c_ws[(size_t)(bbase + quad) * 160 + ixg];
  __syncthreads();

  const uint2* __restrict__ gxp = reinterpret_cast<const uint2*>(gx);
  const size_t goff = (size_t)(bbase + quad) * 160 + ixg;

  auto body = [&](int t, int rb, uint2 g) {
    short8 af[5];
#pragma unroll
    for (int ks = 0; ks < 5; ++ks)
      af[ks] = *reinterpret_cast<const short8*>(&hbuf[rb][mrow][ks * 32 + quad * 8]);
    floatx4 acc[4] = {};
#pragma unroll
    for (int ks = 0; ks < 5; ++ks)
#pragma unroll
      for (int g4 = 0; g4 < 4; ++g4)
        acc[g4] = __builtin_amdgcn_mfma_f32_16x16x32_bf16(af[ks], whf[g4][ks], acc[g4], 0, 0, 0);
    union { uint2 u; unsigned short s[4]; } q;
    q.u = g;
    float xi = acc[0][0] + bfu(q.s[0]);
    float xf = acc[1][0] + bfu(q.s[1]);
    float xg = acc[2][0] + bfu(q.s[2]);
    float xo = acc[3][0] + bfu(q.s[3]);
    float iv = fsig(xi), fv = fsig(xf), gvv = ftanh(xg), ov = fsig(xo);
    c0 = fv * c0 + iv * gvv;
    bf16 hv = f2b(ov * ftanh(c0));
    hbuf[rb ^ 1][quad * 4][ixg] = hv;
    hh[((size_t)t * 256 + bbase + quad) * 160 + ixg] = hv;   // fire-and-forget
  };

  uint2 g0 = gxp[goff];
  uint2 g1 = gxp[(size_t)(256 * 160) + goff];
  for (int t = 0; t < Tc; t += 2) {
    body(t, 0, g0);
    if (t + 2 < Tc) g0 = gxp[(size_t)(t + 2) * (256 * 160) + goff];
    lds_barrier();
    body(t + 1, 1, g1);
    if (t + 3 < Tc) g1 = gxp[(size_t)(t + 3) * (256 * 160) + goff];
    lds_barrier();
  }

  // final state: h after step Tc-1 sits in hbuf[0] (odd step writes buf 0)
  {
    int r = tid / 160, cix = tid - r * 160;
    h_ws[(size_t)(bbase + r) * 160 + cix] = hbuf[0][r * 4][cix];
  }
  c_ws[(size_t)(bbase + quad) * 160 + ixg] = c0;
}

// ---------------- y GEMM: Y = Hhist @ W3^T + b3 ----------------
// One block = 128 rows (waves 0..7 x 16 rows), 32 cols, K=160. Trivial
// throughput work; numerics identical to the old in-recur path (same bf16
// fragments, same 5-ks f32 accumulation order).
__device__ void ygemm(int tid, int yb, const bf16* __restrict__ hh,
                      const bf16* __restrict__ W3w, const float* __restrict__ b3,
                      float* __restrict__ outy)
{
  const int lane = tid & 63, wave = tid >> 6;
  if (wave >= 8) return;
  const int mrow = lane & 15, quad = lane >> 4;
  const size_t R0 = (size_t)yb * 128 + wave * 16;
  short8 af[5], bf0[5], bf1[5];
#pragma unroll
  for (int ks = 0; ks < 5; ++ks) {
    af[ks]  = *reinterpret_cast<const short8*>(&hh[(R0 + mrow) * 160 + ks * 32 + quad * 8]);
    bf0[ks] = *reinterpret_cast<const short8*>(&W3w[(size_t)mrow * 160 + ks * 32 + quad * 8]);
    bf1[ks] = *reinterpret_cast<const short8*>(&W3w[(size_t)(16 + mrow) * 160 + ks * 32 + quad * 8]);
  }
  floatx4 a0 = {}, a1 = {};
#pragma unroll
  for (int ks = 0; ks < 5; ++ks) {
    a0 = __builtin_amdgcn_mfma_f32_16x16x32_bf16(af[ks], bf0[ks], a0, 0, 0, 0);
    a1 = __builtin_amdgcn_mfma_f32_16x16x32_bf16(af[ks], bf1[ks], a1, 0, 0, 0);
  }
  float bb0 = b3[mrow], bb1 = b3[16 + mrow];
#pragma unroll
  for (int r = 0; r < 4; ++r) {
    size_t row = R0 + quad * 4 + r;
    outy[row * 32 + mrow] = a0[r] + bb0;
    outy[row * 32 + 16 + mrow] = a1[r] + bb1;
  }
}

// ---------------- fused pipeline step ----------------
// blocks [0,64): recur(chunk L-1). [64,64+nbg): fused GEMM(chunk L).
// [64+nbg,..): ygemm(chunk L-2) from the h history written one dispatch ago.
__global__ __launch_bounds__(640, 1) void fused_step(
    int has_recur, const bf16* gxr, const bf16* Whh,
    bf16* h_ws, float* c_ws, bf16* hh_w, int Tc, int init,
    int nbg, const bf16* Xc, const bf16* W1w, const float* b1v,
    const bf16* W2w, const float* b2v, const bf16* Wpw,
    const float* bihv, const float* bhhv, bf16* gxw,
    int has_y, const bf16* hh_r, const bf16* W3w, const float* b3, float* outy)
{
  __shared__ __align__(16) char smem[SMEM_BYTES];
  const int tid = threadIdx.x;
  if (blockIdx.x < 64) {
    if (has_recur)
      recur_path(smem, tid, blockIdx.x, gxr, Whh, h_ws, c_ws, hh_w, Tc, init);
    return;
  }
  int gb = blockIdx.x - 64;
  if (gb < nbg) {
    fused_gemm(smem, tid, gb, Xc, W1w, b1v, W2w, b2v, Wpw, bihv, bhhv, gxw);
    return;
  }
  if (has_y)
    ygemm(tid, gb - nbg, hh_r, W3w, b3, outy);
}

// ---------------- launch ----------------
extern "C" void kernel_launch(void* const* d_in, const int* in_sizes, int n_in,
                              void* d_out, int out_size, void* d_ws, size_t ws_size,
                              hipStream_t stream)
{
  const float* inp = (const float*)d_in[0];
  const float* W1  = (const float*)d_in[1];
  const float* b1  = (const float*)d_in[2];
  const float* W2  = (const float*)d_in[3];
  const float* b2  = (const float*)d_in[4];
  const float* Wih = (const float*)d_in[5];
  const float* Whh = (const float*)d_in[6];
  const float* bih = (const float*)d_in[7];
  const float* bhh = (const float*)d_in[8];
  const float* W3  = (const float*)d_in[9];
  const float* b3  = (const float*)d_in[10];
  float* out = (float*)d_out;

  char* ws = (char*)d_ws;
  size_t off = 0;
  auto alloc = [&](size_t bytes) -> char* {
    char* p = ws + off;
    off += (bytes + 255) & ~(size_t)255;
    return p;
  };

  bf16* inpb = (bf16*)alloc((size_t)T_STEPS * BATCH * INW * 2);
  bf16* w1b  = (bf16*)alloc((size_t)H1 * INW * 2);
  bf16* w2b  = (bf16*)alloc((size_t)H4D * H1 * 2);
  bf16* wpb  = (bf16*)alloc((size_t)G4 * H4D * 2);   // permuted W_ih
  bf16* whhb = (bf16*)alloc((size_t)G4 * H8D * 2);
  bf16* w3b  = (bf16*)alloc((size_t)ONUM * H8D * 2);
  bf16* h_ws = (bf16*)alloc((size_t)BATCH * H8D * 2);
  float* c_ws = (float*)alloc((size_t)BATCH * H8D * 4);
  size_t fixed = off;

  // time chunk; double-buffered gate + h-history buffers must fit workspace
  int Tc = 128;
  while (Tc > 16) {
    size_t Mc = (size_t)Tc * BATCH;
    size_t need = fixed
      + 2 * ((Mc * G4 * 2 + 255) & ~(size_t)255)
      + 2 * ((Mc * H8D * 2 + 255) & ~(size_t)255);
    if (need <= ws_size) break;
    Tc >>= 1;
  }
  const size_t Mc = (size_t)Tc * BATCH;
  bf16* gxb[2], *hhb[2];
  for (int i = 0; i < 2; ++i) gxb[i] = (bf16*)alloc(Mc * G4 * 2);
  for (int i = 0; i < 2; ++i) hhb[i] = (bf16*)alloc(Mc * H8D * 2);

  // casts (every call; harness re-poisons ws before each timed launch)
  {
    int n4 = T_STEPS * BATCH * INW / 4;
    cast_f32_bf16_v4<<<(n4 + 255) / 256, 256, 0, stream>>>(inp, inpb, n4);
    n4 = H1 * INW / 4;
    cast_f32_bf16_v4<<<(n4 + 255) / 256, 256, 0, stream>>>(W1, w1b, n4);
    n4 = H4D * H1 / 4;
    cast_f32_bf16_v4<<<(n4 + 255) / 256, 256, 0, stream>>>(W2, w2b, n4);
    int np = G4 * (H4D / 4);
    cast_permute_wih<<<(np + 255) / 256, 256, 0, stream>>>(Wih, wpb);
    n4 = G4 * H8D / 4;
    cast_f32_bf16_v4<<<(n4 + 255) / 256, 256, 0, stream>>>(Whh, whhb, n4);
    n4 = ONUM * H8D / 4;
    cast_f32_bf16_v4<<<(n4 + 255) / 256, 256, 0, stream>>>(W3, w3b, n4);
  }

  const int nch = T_STEPS / Tc;
  const int nGB = (int)(Mc / 64);
  const int nYB = (int)(Mc / 128);

  // Pipeline: dispatch L runs GEMM(L), recur(L-1), ygemm(L-2).
  for (int L = 0; L <= nch + 1; ++L) {
    const int hg = (L < nch) ? 1 : 0;
    const int hr = (L >= 1 && L <= nch) ? 1 : 0;
    const int hy = (L >= 2) ? 1 : 0;
    const int cg = L, cr = L - 1, cy = L - 2;

    const bf16* Xc = inpb + (size_t)(hg ? cg : 0) * Mc * INW;
    bf16* gxw = gxb[cg & 1];
    const bf16* gxr = gxb[(hr ? cr : 0) & 1];
    bf16* hh_w = hhb[(hr ? cr : 0) & 1];
    const bf16* hh_r = hhb[(hy ? cy : 0) & 1];
    float* outy = out + (size_t)(hy ? cy : 0) * Tc * BATCH * ONUM;
    const int nbg = hg ? nGB : 0;
    const int nby = hy ? nYB : 0;

    fused_step<<<64 + nbg + nby, 640, 0, stream>>>(
        hr, gxr, whhb, h_ws, c_ws, hh_w, Tc, (cr == 0) ? 1 : 0,
        nbg, Xc, w1b, b1, w2b, b2, wpb, bih, bhh, gxw,
        hy, hh_r, w3b, b3, outy);
  }
}